// Round 10
// baseline (193.045 us; speedup 1.0000x reference)
//
#include <hip/hip_runtime.h>

#define TS 64
#define NB 256
#define DI 32
#define NH 10
#define IND 42

// DPP quad_perm xor-exchange: 0xB1 = xor1, 0x4E = xor2 (VALU pipe)
template<int CTRL>
__device__ __forceinline__ float dppx(float v){
  return __int_as_float(__builtin_amdgcn_update_dpp(
      0, __float_as_int(v), CTRL, 0xF, 0xF, true));
}

// uniform broadcast from a fixed lane: VALU->SGPR, no LDS
__device__ __forceinline__ float rl(float v, int lane){
  return __int_as_float(__builtin_amdgcn_readlane(__float_as_int(v), lane));
}

__device__ __forceinline__ float sigm(float x){ return 1.f/(1.f + __expf(-x)); }
__device__ __forceinline__ float tanhr(float x){ float e = __expf(2.f*x); return 1.f - 2.f/(e + 1.f); }

// complex helpers on float2 (r,i) — shaped for v_pk_* SLP vectorization
__device__ __forceinline__ float2 cadd(float2 a, float2 b){ return make_float2(a.x+b.x, a.y+b.y); }
__device__ __forceinline__ float2 csub(float2 a, float2 b){ return make_float2(a.x-b.x, a.y-b.y); }
__device__ __forceinline__ float2 cscale(float2 a, float s){ return make_float2(a.x*s, a.y*s); }
__device__ __forceinline__ float2 cmul2(float2 a, float br, float bi){
  return make_float2(a.x*br - a.y*bi, a.x*bi + a.y*br);
}
__device__ __forceinline__ float2 cmulcj(float2 a, float br, float bi){  // a * conj(b)
  return make_float2(a.x*br + a.y*bi, a.y*br - a.x*bi);
}

// combined U = RY(t3)*RX(t2)*RZ(t1) -> 8 floats (row0 r/i pairs, row1 r/i pairs)
__device__ __forceinline__ void mkU(float t1, float t2, float t3, float* dst){
  float c1 = __cosf(0.5f*t1), s1 = __sinf(0.5f*t1);
  float c2 = __cosf(0.5f*t2), s2 = __sinf(0.5f*t2);
  float c3 = __cosf(0.5f*t3), s3 = __sinf(0.5f*t3);
  float A00r =  c2*c1, A00i = -c2*s1;
  float A01r =  s2*s1, A01i = -s2*c1;
  float A10r = -s2*s1, A10i = -s2*c1;
  float A11r =  c2*c1, A11i =  c2*s1;
  dst[0] = c3*A00r - s3*A10r; dst[1] = c3*A00i - s3*A10i;
  dst[2] = c3*A01r - s3*A11r; dst[3] = c3*A01i - s3*A11i;
  dst[4] = s3*A00r + c3*A10r; dst[5] = s3*A00i + c3*A10i;
  dst[6] = s3*A01r + c3*A11r; dst[7] = s3*A01i + c3*A11i;
}

// One block per batch element. Wave g (0..3) = circuit g.
// Heisenberg transfer chain (R9-verified): E_h = Tr(T_0..T_9), lane = h*4 + sigma.
// R10: h-feedback and Vhat broadcast via v_readlane (no LDS round trip);
// chain on float2 (packed f32); activations applied pre-barrier.
__global__ __launch_bounds__(256, 1)
void qlstm_kernel(const float* __restrict__ xin,
                  const float* __restrict__ qp,
                  const float* __restrict__ Wf, const float* __restrict__ bfp,
                  const float* __restrict__ Wi, const float* __restrict__ bip,
                  const float* __restrict__ Wg, const float* __restrict__ bgp,
                  const float* __restrict__ Wo, const float* __restrict__ bop,
                  float* __restrict__ out)
{
  __shared__ __align__(16) float lBw[4][NH][4];   // B_w = U2^dag Z U2 (staging)
  __shared__ float lq[2][4][NH];                  // double-buffered ACTIVATED gate exchange

  const int tid  = threadIdx.x;
  const int b    = blockIdx.x;
  const int g    = tid >> 6;
  const int lane = tid & 63;
  const int hq   = lane >> 2;        // mask index (valid < 10)
  const int sg_  = lane & 3;         // boundary sigma
  const int hrow = (lane < NH) ? lane : 0;

  // ---- init: register-resident weights, layer-1 U, layer-2 B ----
  const float* Wsel = (g==0) ? Wf : (g==1) ? Wi : (g==2) ? Wg : Wo;
  const float* bsel = (g==0) ? bfp : (g==1) ? bip : (g==2) ? bgp : bop;
  float wreg[IND];
  #pragma unroll
  for (int k = 0; k < IND; k++) wreg[k] = Wsel[hrow*IND + k];
  const float breg = bsel[hrow];

  float U1[8];
  mkU(qp[hrow*3+0], qp[hrow*3+1], qp[hrow*3+2], U1);

  if (lane < NH) {
    float u[8];
    mkU(qp[30 + lane*3 + 0], qp[30 + lane*3 + 1], qp[30 + lane*3 + 2], u);
    float B00 = u[0]*u[0]+u[1]*u[1] - (u[4]*u[4]+u[5]*u[5]);
    float B11 = u[2]*u[2]+u[3]*u[3] - (u[6]*u[6]+u[7]*u[7]);
    float B01r= u[0]*u[2]+u[1]*u[3] - (u[4]*u[6]+u[5]*u[7]);
    float B01i= u[1]*u[2]-u[0]*u[3] - (u[5]*u[6]-u[4]*u[7]);
    *reinterpret_cast<float4*>(&lBw[g][lane][0]) = make_float4(B00,B11,B01r,B01i);
  }
  __syncthreads();

  // per-lane pointwise-C constants for wires 1..9 (B_w if w in M_h, delta else)
  float C00[9], C11[9], Cr[9], Ci[9];
  #pragma unroll
  for (int w = 1; w <= 9; w++) {
    float4 bb = *reinterpret_cast<const float4*>(&lBw[g][w][0]);
    bool inM = (hq == 0) || (w <= hq);       // M_0={1..9}, M_h={0..h}
    C00[w-1] = inM ? bb.x : 1.f;
    C11[w-1] = inM ? bb.y : 1.f;
    Cr[w-1]  = inM ? bb.z : 0.f;
    Ci[w-1]  = inM ? bb.w : 0.f;
  }
  // wire-0 kernel, boundary-shifted: K_i = B0e[i ^ sigma] (delta-based for h==0)
  float2 K[4];
  {
    float4 b0 = *reinterpret_cast<const float4*>(&lBw[g][0][0]);
    float er[4] = { b0.x, b0.z, b0.z, b0.y };
    float ei[4] = { 0.f, -b0.w, b0.w, 0.f };
    if (hq == 0) { er[0]=1.f; er[1]=0.f; er[2]=0.f; er[3]=1.f; ei[1]=0.f; ei[2]=0.f; }
    #pragma unroll
    for (int i = 0; i < 4; i++) K[i] = make_float2(er[i ^ sg_], ei[i ^ sg_]);
  }

  // ---- x software pipeline: xf holds x[t+1]; wxc = W.x for current t ----
  const float* xb = xin + (size_t)b*DI;
  float4 xf[8];
  #pragma unroll
  for (int r = 0; r < 8; r++) xf[r] = *reinterpret_cast<const float4*>(xb + r*4);
  float wxc = 0.f;
  #pragma unroll
  for (int r = 0; r < 8; r++) {
    wxc = fmaf(wreg[4*r+0], xf[r].x, wxc);
    wxc = fmaf(wreg[4*r+1], xf[r].y, wxc);
    wxc = fmaf(wreg[4*r+2], xf[r].z, wxc);
    wxc = fmaf(wreg[4*r+3], xf[r].w, wxc);
  }
  #pragma unroll
  for (int r = 0; r < 8; r++)
    xf[r] = *reinterpret_cast<const float4*>(xb + (size_t)1*NB*DI + r*4);

  float cstate = 0.f, hval = 0.f;

  for (int t = 0; t < TS; t++) {
    const int tb = t & 1;

    // ---- (a) h broadcast via readlane; pre-activation; conv data ----
    float pre = wxc + breg;
    #pragma unroll
    for (int j = 0; j < NH; j++) pre = fmaf(wreg[DI+j], rl(hval, j), pre);
    float sh, ch;
    __sincosf(0.5f*pre, &sh, &ch);
    float v0r = U1[0]*ch + U1[2]*sh, v0i = U1[1]*ch + U1[3]*sh;
    float v1r = U1[4]*ch + U1[6]*sh, v1i = U1[5]*ch + U1[7]*sh;
    // wire 0 keeps plain products; wires 1-9 store WHT'd (V0,V1)/2 products
    float A0r, A0i, A1r, A1i;
    if (lane == 0) { A0r=v0r; A0i=v0i; A1r=v1r; A1i=v1i; }
    else { A0r=0.5f*(v0r+v1r); A0i=0.5f*(v0i+v1i);
           A1r=0.5f*(v0r-v1r); A1i=0.5f*(v0i-v1i); }
    float n0v  = A0r*A0r + A0i*A0i;
    float n1v  = A1r*A1r + A1i*A1i;
    float e1rv = A1r*A0r + A1i*A0i;
    float e1iv = A1i*A0r - A1r*A0i;

    // broadcast all wires' conv data via readlane (uniform -> SGPRs)
    float vx[NH], vy[NH], ver[NH], vei[NH];
    #pragma unroll
    for (int w = 0; w < NH; w++) {
      vx[w]  = rl(n0v,  w);
      vy[w]  = rl(n1v,  w);
      ver[w] = rl(e1rv, w);
      vei[w] = rl(e1iv, w);
    }

    // ---- pipeline advance: Wx for t+1, load x for t+2 ----
    float wxn = 0.f;
    #pragma unroll
    for (int r = 0; r < 8; r++) {
      wxn = fmaf(wreg[4*r+0], xf[r].x, wxn);
      wxn = fmaf(wreg[4*r+1], xf[r].y, wxn);
      wxn = fmaf(wreg[4*r+2], xf[r].z, wxn);
      wxn = fmaf(wreg[4*r+3], xf[r].w, wxn);
    }
    {
      int tn = (t + 2 < TS) ? t + 2 : 0;
      #pragma unroll
      for (int r = 0; r < 8; r++)
        xf[r] = *reinterpret_cast<const float4*>(xb + (size_t)tn*NB*DI + r*4);
    }

    // ---- (c) transfer chain (float2 / packed f32) ----
    float2 r0 = cscale(K[0], vx[0]);
    float2 r3 = cscale(K[3], vy[0]);
    float2 r1 = cmul2 (K[1], ver[0], vei[0]);
    float2 r2 = cmulcj(K[2], ver[0], vei[0]);

    #pragma unroll
    for (int w = 1; w <= 9; w++) {
      // 2-bit WHT
      float2 a  = cadd(r0, r1), bb = csub(r0, r1);
      float2 c2 = cadd(r2, r3), d  = csub(r2, r3);
      float2 u0 = cadd(a, c2),  u2 = csub(a, c2);
      float2 u1 = cadd(bb, d),  u3 = csub(bb, d);
      // pointwise Vhat
      float2 m0 = cscale(u0, vx[w]);
      float2 m3 = cscale(u3, vy[w]);
      float2 m1 = cmul2 (u1, ver[w], vei[w]);
      float2 m2 = cmulcj(u2, ver[w], vei[w]);
      // inverse WHT (scale folded into Vhat)
      float2 p0 = cadd(m0, m1), p1 = csub(m0, m1);
      float2 p2 = cadd(m2, m3), p3 = csub(m2, m3);
      float2 y0 = cadd(p0, p2), y2 = csub(p0, p2);
      float2 y1 = cadd(p1, p3), y3 = csub(p1, p3);
      // pointwise C (Hermitian; delta off-mask)
      r0 = cscale(y0, C00[w-1]);
      r3 = cscale(y3, C11[w-1]);
      r1 = cmulcj(y1, Cr[w-1], Ci[w-1]);
      r2 = cmul2 (y2, Cr[w-1], Ci[w-1]);
    }

    // ---- (d) trace + quad-sum; activation PRE-barrier ----
    float t0 = (lane & 1) ? r1.x : r0.x;
    float t1 = (lane & 1) ? r3.x : r2.x;
    float Ee = (lane & 2) ? t1 : t0;
    Ee += dppx<0xB1>(Ee);
    Ee += dppx<0x4E>(Ee);
    if ((lane & 3) == 0 && hq < NH) {
      float a = (g == 2) ? tanhr(Ee) : sigm(Ee);
      lq[tb][g][hq] = a;
    }
    __syncthreads();   // the one barrier: activated-gate exchange

    // ---- (f) LSTM cell (all lanes, clamped row; lanes>=10 mirror lane 0) ----
    float fv = lq[tb][0][hrow];
    float iv = lq[tb][1][hrow];
    float gv = lq[tb][2][hrow];
    float ov = lq[tb][3][hrow];
    cstate = fv*cstate + iv*gv;
    hval = ov*tanhr(cstate);
    if (g == 0 && lane < NH) out[(size_t)t*(NB*NH) + b*NH + lane] = hval;
    wxc = wxn;
  }

  if (g == 0 && lane < NH) {
    out[(size_t)TS*NB*NH + b*NH + lane]          = hval;
    out[(size_t)TS*NB*NH + NB*NH + b*NH + lane]  = cstate;
  }
}

extern "C" void kernel_launch(void* const* d_in, const int* in_sizes, int n_in,
                              void* d_out, int out_size, void* d_ws, size_t ws_size,
                              hipStream_t stream) {
  (void)in_sizes; (void)n_in; (void)d_ws; (void)ws_size; (void)out_size;
  qlstm_kernel<<<dim3(NB), dim3(256), 0, stream>>>(
      (const float*)d_in[0], (const float*)d_in[1],
      (const float*)d_in[2], (const float*)d_in[3],
      (const float*)d_in[4], (const float*)d_in[5],
      (const float*)d_in[6], (const float*)d_in[7],
      (const float*)d_in[8], (const float*)d_in[9],
      (float*)d_out);
}

// Round 11
// 127.189 us; speedup vs baseline: 1.5178x; 1.5178x over previous
//
#include <hip/hip_runtime.h>

#define TS 64
#define NB 256
#define DI 32
#define NH 10
#define IND 42

// DPP quad_perm xor-exchange: 0xB1 = xor1, 0x4E = xor2 (VALU pipe)
template<int CTRL>
__device__ __forceinline__ float dppx(float v){
  return __int_as_float(__builtin_amdgcn_update_dpp(
      0, __float_as_int(v), CTRL, 0xF, 0xF, true));
}

// uniform broadcast from a fixed lane: VALU->SGPR, no LDS
__device__ __forceinline__ float rl(float v, int lane){
  return __int_as_float(__builtin_amdgcn_readlane(__float_as_int(v), lane));
}

__device__ __forceinline__ float sigm(float x){ return 1.f/(1.f + __expf(-x)); }
__device__ __forceinline__ float tanhr(float x){ float e = __expf(2.f*x); return 1.f - 2.f/(e + 1.f); }

// combined U = RY(t3)*RX(t2)*RZ(t1) -> 8 floats (row0 r/i pairs, row1 r/i pairs)
__device__ __forceinline__ void mkU(float t1, float t2, float t3, float* dst){
  float c1 = __cosf(0.5f*t1), s1 = __sinf(0.5f*t1);
  float c2 = __cosf(0.5f*t2), s2 = __sinf(0.5f*t2);
  float c3 = __cosf(0.5f*t3), s3 = __sinf(0.5f*t3);
  float A00r =  c2*c1, A00i = -c2*s1;
  float A01r =  s2*s1, A01i = -s2*c1;
  float A10r = -s2*s1, A10i = -s2*c1;
  float A11r =  c2*c1, A11i =  c2*s1;
  dst[0] = c3*A00r - s3*A10r; dst[1] = c3*A00i - s3*A10i;
  dst[2] = c3*A01r - s3*A11r; dst[3] = c3*A01i - s3*A11i;
  dst[4] = s3*A00r + c3*A10r; dst[5] = s3*A00i + c3*A10i;
  dst[6] = s3*A01r + c3*A11r; dst[7] = s3*A01i + c3*A11i;
}

// One block per batch element. Wave g (0..3) = circuit g.
// Heisenberg chain (R9-verified), Hermitian 4-real form:
//   lane = hq*4 + sg; sg=0 -> sigma0 slice, sg=1 -> H1, sg=2 -> H2, sg=3 -> sigma3.
//   Each lane propagates (r0, r3, a, b) = (entry0, entry3, Re e1, Im e1) through
//   9 wires of WHT -> Vhat -> invWHT -> C, all real arithmetic (24 instr/wire).
//   E = r0(sg0) + 2a(H1) - 2b(H2) + r3(sg3)  [sigma1 & sigma2 contributions equal].
// W.x precomputed for all t (t-parallel, outside recurrence).
__global__ __launch_bounds__(256, 1)
void qlstm_kernel(const float* __restrict__ xin,
                  const float* __restrict__ qp,
                  const float* __restrict__ Wf, const float* __restrict__ bfp,
                  const float* __restrict__ Wi, const float* __restrict__ bip,
                  const float* __restrict__ Wg, const float* __restrict__ bgp,
                  const float* __restrict__ Wo, const float* __restrict__ bop,
                  float* __restrict__ out)
{
  __shared__ float lx[TS][DI + 1];                // staged x, +1 pad (bank-safe)
  __shared__ float lwx[4][TS][NH];                // precomputed W.x + bias
  __shared__ __align__(16) float lBw[4][NH][4];   // B_w = U2^dag Z U2
  __shared__ float lq[2][4][NH];                  // double-buffered activated gates

  const int tid  = threadIdx.x;
  const int b    = blockIdx.x;
  const int g    = tid >> 6;
  const int lane = tid & 63;
  const int hq   = lane >> 2;        // mask index (valid < 10)
  const int sg   = lane & 3;         // 0:sigma0 1:H1 2:H2 3:sigma3
  const int hrow = (lane < NH) ? lane : 0;

  const float* Wsel = (g==0) ? Wf : (g==1) ? Wi : (g==2) ? Wg : Wo;
  const float* bsel = (g==0) ? bfp : (g==1) ? bip : (g==2) ? bgp : bop;

  // ---- stage x coalesced ----
  for (int i = tid; i < TS*DI; i += 256) {
    int tt = i >> 5, d = i & 31;
    lx[tt][d] = xin[(size_t)tt*(NB*DI) + b*DI + d];
  }
  // ---- layer-2 B matrices ----
  if (lane < NH) {
    float u[8];
    mkU(qp[30 + lane*3 + 0], qp[30 + lane*3 + 1], qp[30 + lane*3 + 2], u);
    float B00 = u[0]*u[0]+u[1]*u[1] - (u[4]*u[4]+u[5]*u[5]);
    float B11 = u[2]*u[2]+u[3]*u[3] - (u[6]*u[6]+u[7]*u[7]);
    float B01r= u[0]*u[2]+u[1]*u[3] - (u[4]*u[6]+u[5]*u[7]);
    float B01i= u[1]*u[2]-u[0]*u[3] - (u[5]*u[6]-u[4]*u[7]);
    *reinterpret_cast<float4*>(&lBw[g][lane][0]) = make_float4(B00,B11,B01r,B01i);
  }
  __syncthreads();

  // ---- precompute W.x + bias for all t (lane == t), wave-private lwx[g] ----
  {
    float acc[NH];
    #pragma unroll
    for (int h = 0; h < NH; h++) acc[h] = bsel[h];
    for (int k = 0; k < DI; k++) {
      float xk = lx[lane][k];
      #pragma unroll
      for (int h = 0; h < NH; h++) acc[h] = fmaf(Wsel[h*IND + k], xk, acc[h]);
    }
    #pragma unroll
    for (int h = 0; h < NH; h++) lwx[g][lane][h] = acc[h];
  }
  // (same-wave LDS visibility via lgkmcnt; no barrier needed for lwx/lBw use below)

  // ---- register-resident recurrent weights + layer-1 U for row hrow ----
  float wh[NH];
  #pragma unroll
  for (int j = 0; j < NH; j++) wh[j] = Wsel[hrow*IND + DI + j];
  float U1[8];
  mkU(qp[hrow*3+0], qp[hrow*3+1], qp[hrow*3+2], U1);

  // ---- per-lane chain constants ----
  float4 b0 = *reinterpret_cast<const float4*>(&lBw[g][0][0]);
  if (hq == 0) b0 = make_float4(1.f, 1.f, 0.f, 0.f);   // E0 mask excludes wire 0
  float k0, k3, ka, kb;
  if      (sg == 0) { k0 = b0.x;  k3 = b0.y;  ka = b0.z; kb = -b0.w; }
  else if (sg == 1) { k0 = b0.z;  k3 = b0.z;  ka = 0.5f*(b0.x + b0.y); kb = 0.f; }
  else if (sg == 2) { k0 = -b0.w; k3 = b0.w;  ka = 0.f;  kb = 0.5f*(b0.y - b0.x); }
  else              { k0 = b0.y;  k3 = b0.x;  ka = b0.z; kb = b0.w; }
  const float pw = (sg == 1) ? 2.f : (sg == 2) ? -2.f : 1.f;

  float C00[9], C11[9], Cr[9], Ci[9];
  #pragma unroll
  for (int w = 1; w <= 9; w++) {
    float4 bb = *reinterpret_cast<const float4*>(&lBw[g][w][0]);
    bool inM = (hq == 0) || (w <= hq);        // M_0={1..9}, M_h={0..h}
    C00[w-1] = inM ? bb.x : 1.f;
    C11[w-1] = inM ? bb.y : 1.f;
    Cr[w-1]  = inM ? bb.z : 0.f;
    Ci[w-1]  = inM ? bb.w : 0.f;
  }

  float cstate = 0.f, hval = 0.f;

  for (int t = 0; t < TS; t++) {
    const int tb = t & 1;

    // ---- (a) pre-activation: LDS wx + recurrent part via readlane ----
    float pre = lwx[g][t][hrow];
    #pragma unroll
    for (int j = 0; j < NH; j++) pre = fmaf(wh[j], rl(hval, j), pre);
    float sh, ch;
    __sincosf(0.5f*pre, &sh, &ch);
    float v0r = U1[0]*ch + U1[2]*sh, v0i = U1[1]*ch + U1[3]*sh;
    float v1r = U1[4]*ch + U1[6]*sh, v1i = U1[5]*ch + U1[7]*sh;
    // wire 0 keeps plain products; wires 1-9 store WHT'd (V0,V1)/2 products
    float A0r, A0i, A1r, A1i;
    if (lane == 0) { A0r=v0r; A0i=v0i; A1r=v1r; A1i=v1i; }
    else { A0r=0.5f*(v0r+v1r); A0i=0.5f*(v0i+v1i);
           A1r=0.5f*(v0r-v1r); A1i=0.5f*(v0i-v1i); }
    float n0v  = A0r*A0r + A0i*A0i;
    float n1v  = A1r*A1r + A1i*A1i;
    float e1rv = A1r*A0r + A1i*A0i;
    float e1iv = A1i*A0r - A1r*A0i;

    // broadcast all wires' conv data (wave-uniform -> SGPRs)
    float vx[NH], vy[NH], ver[NH], vei[NH];
    #pragma unroll
    for (int w = 0; w < NH; w++) {
      vx[w]  = rl(n0v,  w);
      vy[w]  = rl(n1v,  w);
      ver[w] = rl(e1rv, w);
      vei[w] = rl(e1iv, w);
    }

    // ---- (c) Hermitian 4-real transfer chain ----
    float r0 = k0*vx[0];
    float r3 = k3*vy[0];
    float a  = ka*ver[0] - kb*vei[0];
    float bz = ka*vei[0] + kb*ver[0];
    #pragma unroll
    for (int w = 1; w <= 9; w++) {
      float q  = r0 + r3,  t2a = a + a;
      float u0 = q + t2a,  u3 = q - t2a;
      float s  = r0 - r3,  bb = bz + bz;          // u1 = (s, -bb)
      float m0 = u0 * vx[w];
      float m3 = u3 * vy[w];
      float am = s*ver[w] + bb*vei[w];            // Re(u1*e1)
      float bm = s*vei[w] - bb*ver[w];            // Im(u1*e1)
      float q2 = m0 + m3,  t2m = am + am;
      float y0 = q2 + t2m, y3 = q2 - t2m;
      float s2 = m0 - m3,  b2 = bm + bm;          // y1 = (s2, -b2)
      r0 = y0 * C00[w-1];
      r3 = y3 * C11[w-1];
      a  = s2*Cr[w-1] - b2*Ci[w-1];               // Re(y1*conj(C01))
      bz = -(s2*Ci[w-1] + b2*Cr[w-1]);            // Im(y1*conj(C01))
    }

    // ---- (d) weighted pick + quad-sum; activation PRE-barrier ----
    float t0 = (sg & 1) ? a  : r0;
    float t1 = (sg & 1) ? r3 : bz;
    float Ee = ((sg & 2) ? t1 : t0) * pw;
    Ee += dppx<0xB1>(Ee);
    Ee += dppx<0x4E>(Ee);
    if ((lane & 3) == 0 && hq < NH) {
      lq[tb][g][hq] = (g == 2) ? tanhr(Ee) : sigm(Ee);
    }
    __syncthreads();   // the one barrier: activated-gate exchange

    // ---- (f) LSTM cell (all lanes, clamped row; lanes>=10 mirror lane 0) ----
    float fv = lq[tb][0][hrow];
    float iv = lq[tb][1][hrow];
    float gv = lq[tb][2][hrow];
    float ov = lq[tb][3][hrow];
    cstate = fv*cstate + iv*gv;
    hval = ov*tanhr(cstate);
    if (g == 0 && lane < NH) out[(size_t)t*(NB*NH) + b*NH + lane] = hval;
  }

  if (g == 0 && lane < NH) {
    out[(size_t)TS*NB*NH + b*NH + lane]          = hval;
    out[(size_t)TS*NB*NH + NB*NH + b*NH + lane]  = cstate;
  }
}

extern "C" void kernel_launch(void* const* d_in, const int* in_sizes, int n_in,
                              void* d_out, int out_size, void* d_ws, size_t ws_size,
                              hipStream_t stream) {
  (void)in_sizes; (void)n_in; (void)d_ws; (void)ws_size; (void)out_size;
  qlstm_kernel<<<dim3(NB), dim3(256), 0, stream>>>(
      (const float*)d_in[0], (const float*)d_in[1],
      (const float*)d_in[2], (const float*)d_in[3],
      (const float*)d_in[4], (const float*)d_in[5],
      (const float*)d_in[6], (const float*)d_in[7],
      (const float*)d_in[8], (const float*)d_in[9],
      (float*)d_out);
}

// Round 12
// 126.301 us; speedup vs baseline: 1.5285x; 1.0070x over previous
//
#include <hip/hip_runtime.h>

#define TS 64
#define NB 256
#define DI 32
#define NH 10
#define IND 42

// DPP quad_perm xor-exchange: 0xB1 = xor1, 0x4E = xor2 (VALU pipe)
template<int CTRL>
__device__ __forceinline__ float dppx(float v){
  return __int_as_float(__builtin_amdgcn_update_dpp(
      0, __float_as_int(v), CTRL, 0xF, 0xF, true));
}

// uniform broadcast from a fixed lane: VALU->SGPR, no LDS
__device__ __forceinline__ float rl(float v, int lane){
  return __int_as_float(__builtin_amdgcn_readlane(__float_as_int(v), lane));
}

__device__ __forceinline__ float sigm(float x){ return 1.f/(1.f + __expf(-x)); }
__device__ __forceinline__ float tanhr(float x){ float e = __expf(2.f*x); return 1.f - 2.f/(e + 1.f); }

// combined U = RY(t3)*RX(t2)*RZ(t1) -> 8 floats (row0 r/i pairs, row1 r/i pairs)
__device__ __forceinline__ void mkU(float t1, float t2, float t3, float* dst){
  float c1 = __cosf(0.5f*t1), s1 = __sinf(0.5f*t1);
  float c2 = __cosf(0.5f*t2), s2 = __sinf(0.5f*t2);
  float c3 = __cosf(0.5f*t3), s3 = __sinf(0.5f*t3);
  float A00r =  c2*c1, A00i = -c2*s1;
  float A01r =  s2*s1, A01i = -s2*c1;
  float A10r = -s2*s1, A10i = -s2*c1;
  float A11r =  c2*c1, A11i =  c2*s1;
  dst[0] = c3*A00r - s3*A10r; dst[1] = c3*A00i - s3*A10i;
  dst[2] = c3*A01r - s3*A11r; dst[3] = c3*A01i - s3*A11i;
  dst[4] = s3*A00r + c3*A10r; dst[5] = s3*A00i + c3*A10i;
  dst[6] = s3*A01r + c3*A11r; dst[7] = s3*A01i + c3*A11i;
}

// One block per batch element. Wave g (0..3) = circuit g.
// Heisenberg chain (R9/R11-verified), Hermitian 4-real form.
// R12: lq as [t][h][gate] for single b128 exchange read; tree-reduced h-dot;
// lwx prefetch one step ahead.
__global__ __launch_bounds__(256, 1)
void qlstm_kernel(const float* __restrict__ xin,
                  const float* __restrict__ qp,
                  const float* __restrict__ Wf, const float* __restrict__ bfp,
                  const float* __restrict__ Wi, const float* __restrict__ bip,
                  const float* __restrict__ Wg, const float* __restrict__ bgp,
                  const float* __restrict__ Wo, const float* __restrict__ bop,
                  float* __restrict__ out)
{
  __shared__ float lx[TS][DI + 1];                // staged x, +1 pad
  __shared__ float lwx[4][TS][NH];                // precomputed W.x + bias
  __shared__ __align__(16) float lBw[4][NH][4];   // B_w = U2^dag Z U2
  __shared__ __align__(16) float lq[2][NH][4];    // [buf][h][gate] -> b128 read

  const int tid  = threadIdx.x;
  const int b    = blockIdx.x;
  const int g    = tid >> 6;
  const int lane = tid & 63;
  const int hq   = lane >> 2;        // mask index (valid < 10)
  const int sg   = lane & 3;         // 0:sigma0 1:H1 2:H2 3:sigma3
  const int hrow = (lane < NH) ? lane : 0;

  const float* Wsel = (g==0) ? Wf : (g==1) ? Wi : (g==2) ? Wg : Wo;
  const float* bsel = (g==0) ? bfp : (g==1) ? bip : (g==2) ? bgp : bop;

  // ---- stage x coalesced ----
  for (int i = tid; i < TS*DI; i += 256) {
    int tt = i >> 5, d = i & 31;
    lx[tt][d] = xin[(size_t)tt*(NB*DI) + b*DI + d];
  }
  // ---- layer-2 B matrices ----
  if (lane < NH) {
    float u[8];
    mkU(qp[30 + lane*3 + 0], qp[30 + lane*3 + 1], qp[30 + lane*3 + 2], u);
    float B00 = u[0]*u[0]+u[1]*u[1] - (u[4]*u[4]+u[5]*u[5]);
    float B11 = u[2]*u[2]+u[3]*u[3] - (u[6]*u[6]+u[7]*u[7]);
    float B01r= u[0]*u[2]+u[1]*u[3] - (u[4]*u[6]+u[5]*u[7]);
    float B01i= u[1]*u[2]-u[0]*u[3] - (u[5]*u[6]-u[4]*u[7]);
    *reinterpret_cast<float4*>(&lBw[g][lane][0]) = make_float4(B00,B11,B01r,B01i);
  }
  __syncthreads();

  // ---- precompute W.x + bias for all t (lane == t), wave-private lwx[g] ----
  {
    float acc[NH];
    #pragma unroll
    for (int h = 0; h < NH; h++) acc[h] = bsel[h];
    for (int k = 0; k < DI; k++) {
      float xk = lx[lane][k];
      #pragma unroll
      for (int h = 0; h < NH; h++) acc[h] = fmaf(Wsel[h*IND + k], xk, acc[h]);
    }
    #pragma unroll
    for (int h = 0; h < NH; h++) lwx[g][lane][h] = acc[h];
  }
  // (same-wave LDS visibility via lgkmcnt)

  // ---- register-resident recurrent weights + layer-1 U for row hrow ----
  float wh[NH];
  #pragma unroll
  for (int j = 0; j < NH; j++) wh[j] = Wsel[hrow*IND + DI + j];
  float U1[8];
  mkU(qp[hrow*3+0], qp[hrow*3+1], qp[hrow*3+2], U1);

  // ---- per-lane chain constants ----
  float4 b0 = *reinterpret_cast<const float4*>(&lBw[g][0][0]);
  if (hq == 0) b0 = make_float4(1.f, 1.f, 0.f, 0.f);   // E0 mask excludes wire 0
  float k0, k3, ka, kb;
  if      (sg == 0) { k0 = b0.x;  k3 = b0.y;  ka = b0.z; kb = -b0.w; }
  else if (sg == 1) { k0 = b0.z;  k3 = b0.z;  ka = 0.5f*(b0.x + b0.y); kb = 0.f; }
  else if (sg == 2) { k0 = -b0.w; k3 = b0.w;  ka = 0.f;  kb = 0.5f*(b0.y - b0.x); }
  else              { k0 = b0.y;  k3 = b0.x;  ka = b0.z; kb = b0.w; }
  const float pw = (sg == 1) ? 2.f : (sg == 2) ? -2.f : 1.f;

  float C00[9], C11[9], Cr[9], Ci[9];
  #pragma unroll
  for (int w = 1; w <= 9; w++) {
    float4 bb = *reinterpret_cast<const float4*>(&lBw[g][w][0]);
    bool inM = (hq == 0) || (w <= hq);        // M_0={1..9}, M_h={0..h}
    C00[w-1] = inM ? bb.x : 1.f;
    C11[w-1] = inM ? bb.y : 1.f;
    Cr[w-1]  = inM ? bb.z : 0.f;
    Ci[w-1]  = inM ? bb.w : 0.f;
  }

  float cstate = 0.f, hval = 0.f;
  float wxcur = lwx[g][0][hrow];      // prefetched W.x for t=0

  for (int t = 0; t < TS; t++) {
    const int tb = t & 1;

    // ---- (a) pre-activation: prefetched wx + tree-reduced recurrent dot ----
    float h0 = rl(hval,0), h1 = rl(hval,1), h2 = rl(hval,2), h3 = rl(hval,3), h4 = rl(hval,4);
    float h5 = rl(hval,5), h6 = rl(hval,6), h7 = rl(hval,7), h8 = rl(hval,8), h9 = rl(hval,9);
    float p0 = fmaf(wh[1], h1, wh[0]*h0);
    float p1 = fmaf(wh[3], h3, wh[2]*h2);
    float p2 = fmaf(wh[5], h5, wh[4]*h4);
    float p3 = fmaf(wh[7], h7, wh[6]*h6);
    float p4 = fmaf(wh[9], h9, wh[8]*h8);
    float pre = wxcur + ((p0 + p1) + (p2 + p3) + p4);

    // prefetch next step's W.x (latency hidden under the chain)
    if (t + 1 < TS) wxcur = lwx[g][t+1][hrow];

    float sh, ch;
    __sincosf(0.5f*pre, &sh, &ch);
    float v0r = U1[0]*ch + U1[2]*sh, v0i = U1[1]*ch + U1[3]*sh;
    float v1r = U1[4]*ch + U1[6]*sh, v1i = U1[5]*ch + U1[7]*sh;
    // wire 0 keeps plain products; wires 1-9 store WHT'd (V0,V1)/2 products
    float A0r, A0i, A1r, A1i;
    if (lane == 0) { A0r=v0r; A0i=v0i; A1r=v1r; A1i=v1i; }
    else { A0r=0.5f*(v0r+v1r); A0i=0.5f*(v0i+v1i);
           A1r=0.5f*(v0r-v1r); A1i=0.5f*(v0i-v1i); }
    float n0v  = A0r*A0r + A0i*A0i;
    float n1v  = A1r*A1r + A1i*A1i;
    float e1rv = A1r*A0r + A1i*A0i;
    float e1iv = A1i*A0r - A1r*A0i;

    // ---- (c) chain with broadcasts interleaved at point of use ----
    float vx0 = rl(n0v,0), vy0 = rl(n1v,0), vr0 = rl(e1rv,0), vi0 = rl(e1iv,0);
    float r0 = k0*vx0;
    float r3 = k3*vy0;
    float a  = ka*vr0 - kb*vi0;
    float bz = ka*vi0 + kb*vr0;
    #pragma unroll
    for (int w = 1; w <= 9; w++) {
      float vxw = rl(n0v, w), vyw = rl(n1v, w), vrw = rl(e1rv, w), viw = rl(e1iv, w);
      float q  = r0 + r3,  t2a = a + a;
      float u0 = q + t2a,  u3 = q - t2a;
      float s  = r0 - r3,  bb = bz + bz;          // u1 = (s, -bb)
      float m0 = u0 * vxw;
      float m3 = u3 * vyw;
      float am = s*vrw + bb*viw;                  // Re(u1*e1)
      float bm = s*viw - bb*vrw;                  // Im(u1*e1)
      float q2 = m0 + m3,  t2m = am + am;
      float y0 = q2 + t2m, y3 = q2 - t2m;
      float s2 = m0 - m3,  b2 = bm + bm;          // y1 = (s2, -b2)
      r0 = y0 * C00[w-1];
      r3 = y3 * C11[w-1];
      a  = s2*Cr[w-1] - b2*Ci[w-1];               // Re(y1*conj(C01))
      bz = -(s2*Ci[w-1] + b2*Cr[w-1]);            // Im(y1*conj(C01))
    }

    // ---- (d) weighted pick + quad-sum; activation PRE-barrier ----
    float t0 = (sg & 1) ? a  : r0;
    float t1 = (sg & 1) ? r3 : bz;
    float Ee = ((sg & 2) ? t1 : t0) * pw;
    Ee += dppx<0xB1>(Ee);
    Ee += dppx<0x4E>(Ee);
    if ((lane & 3) == 0 && hq < NH) {
      lq[tb][hq][g] = (g == 2) ? tanhr(Ee) : sigm(Ee);
    }
    __syncthreads();   // the one barrier: activated-gate exchange

    // ---- (f) LSTM cell: single b128 broadcast read of (f,i,g,o) ----
    float4 gates = *reinterpret_cast<const float4*>(&lq[tb][hrow][0]);
    cstate = gates.x*cstate + gates.y*gates.z;
    hval = gates.w*tanhr(cstate);
    if (g == 0 && lane < NH) out[(size_t)t*(NB*NH) + b*NH + lane] = hval;
  }

  if (g == 0 && lane < NH) {
    out[(size_t)TS*NB*NH + b*NH + lane]          = hval;
    out[(size_t)TS*NB*NH + NB*NH + b*NH + lane]  = cstate;
  }
}

extern "C" void kernel_launch(void* const* d_in, const int* in_sizes, int n_in,
                              void* d_out, int out_size, void* d_ws, size_t ws_size,
                              hipStream_t stream) {
  (void)in_sizes; (void)n_in; (void)d_ws; (void)ws_size; (void)out_size;
  qlstm_kernel<<<dim3(NB), dim3(256), 0, stream>>>(
      (const float*)d_in[0], (const float*)d_in[1],
      (const float*)d_in[2], (const float*)d_in[3],
      (const float*)d_in[4], (const float*)d_in[5],
      (const float*)d_in[6], (const float*)d_in[7],
      (const float*)d_in[8], (const float*)d_in[9],
      (float*)d_out);
}

// Round 13
// 125.668 us; speedup vs baseline: 1.5362x; 1.0050x over previous
//
#include <hip/hip_runtime.h>

#define TS 64
#define NB 256
#define DI 32
#define NH 10
#define IND 42

// DPP quad_perm xor-exchange: 0xB1 = xor1, 0x4E = xor2 (VALU pipe)
template<int CTRL>
__device__ __forceinline__ float dppx(float v){
  return __int_as_float(__builtin_amdgcn_update_dpp(
      0, __float_as_int(v), CTRL, 0xF, 0xF, true));
}

// uniform broadcast from a fixed lane: VALU->SGPR, no LDS
__device__ __forceinline__ float rl(float v, int lane){
  return __int_as_float(__builtin_amdgcn_readlane(__float_as_int(v), lane));
}

__device__ __forceinline__ float sigm(float x){ return 1.f/(1.f + __expf(-x)); }
__device__ __forceinline__ float tanhr(float x){ float e = __expf(2.f*x); return 1.f - 2.f/(e + 1.f); }

// combined U = RY(t3)*RX(t2)*RZ(t1) -> 8 floats (row0 r/i pairs, row1 r/i pairs)
__device__ __forceinline__ void mkU(float t1, float t2, float t3, float* dst){
  float c1 = __cosf(0.5f*t1), s1 = __sinf(0.5f*t1);
  float c2 = __cosf(0.5f*t2), s2 = __sinf(0.5f*t2);
  float c3 = __cosf(0.5f*t3), s3 = __sinf(0.5f*t3);
  float A00r =  c2*c1, A00i = -c2*s1;
  float A01r =  s2*s1, A01i = -s2*c1;
  float A10r = -s2*s1, A10i = -s2*c1;
  float A11r =  c2*c1, A11i =  c2*s1;
  dst[0] = c3*A00r - s3*A10r; dst[1] = c3*A00i - s3*A10i;
  dst[2] = c3*A01r - s3*A11r; dst[3] = c3*A01i - s3*A11i;
  dst[4] = s3*A00r + c3*A10r; dst[5] = s3*A00i + c3*A10i;
  dst[6] = s3*A01r + c3*A11r; dst[7] = s3*A01i + c3*A11i;
}

// quadratic form q00*c^2 + q11*s^2 + q01*c*s  ->  (alpha, beta, gamma) s.t.
// value = alpha + beta*cos(th) + gamma*sin(th), with (c,s)=(cos(th/2),sin(th/2))
__device__ __forceinline__ float3 qf(float q00, float q11, float q01){
  return make_float3(0.5f*(q00+q11), 0.5f*(q00-q11), 0.5f*q01);
}
__device__ __forceinline__ float qeval(float3 q, float C, float S){
  return fmaf(q.y, C, fmaf(q.z, S, q.x));
}

// One block per batch element. Wave g (0..3) = circuit g.
// Heisenberg chain (R9/R11-verified), Hermitian 4-real form.
// R13: conv data as quadratic forms (8 FMA from cos/sin of FULL angle pre),
// raw v_sin/v_cos (no range reduction), branchless wx prefetch.
__global__ __launch_bounds__(256, 1)
void qlstm_kernel(const float* __restrict__ xin,
                  const float* __restrict__ qp,
                  const float* __restrict__ Wf, const float* __restrict__ bfp,
                  const float* __restrict__ Wi, const float* __restrict__ bip,
                  const float* __restrict__ Wg, const float* __restrict__ bgp,
                  const float* __restrict__ Wo, const float* __restrict__ bop,
                  float* __restrict__ out)
{
  __shared__ float lx[TS][DI + 1];                // staged x, +1 pad
  __shared__ float lwx[4][TS][NH];                // precomputed W.x + bias
  __shared__ __align__(16) float lBw[4][NH][4];   // B_w = U2^dag Z U2
  __shared__ __align__(16) float lq[2][NH][4];    // [buf][h][gate] -> b128 read

  const int tid  = threadIdx.x;
  const int b    = blockIdx.x;
  const int g    = tid >> 6;
  const int lane = tid & 63;
  const int hq   = lane >> 2;        // mask index (valid < 10)
  const int sg   = lane & 3;         // 0:sigma0 1:H1 2:H2 3:sigma3
  const int hrow = (lane < NH) ? lane : 0;

  const float* Wsel = (g==0) ? Wf : (g==1) ? Wi : (g==2) ? Wg : Wo;
  const float* bsel = (g==0) ? bfp : (g==1) ? bip : (g==2) ? bgp : bop;

  // ---- stage x coalesced ----
  for (int i = tid; i < TS*DI; i += 256) {
    int tt = i >> 5, d = i & 31;
    lx[tt][d] = xin[(size_t)tt*(NB*DI) + b*DI + d];
  }
  // ---- layer-2 B matrices ----
  if (lane < NH) {
    float u[8];
    mkU(qp[30 + lane*3 + 0], qp[30 + lane*3 + 1], qp[30 + lane*3 + 2], u);
    float B00 = u[0]*u[0]+u[1]*u[1] - (u[4]*u[4]+u[5]*u[5]);
    float B11 = u[2]*u[2]+u[3]*u[3] - (u[6]*u[6]+u[7]*u[7]);
    float B01r= u[0]*u[2]+u[1]*u[3] - (u[4]*u[6]+u[5]*u[7]);
    float B01i= u[1]*u[2]-u[0]*u[3] - (u[5]*u[6]-u[4]*u[7]);
    *reinterpret_cast<float4*>(&lBw[g][lane][0]) = make_float4(B00,B11,B01r,B01i);
  }
  __syncthreads();

  // ---- precompute W.x + bias for all t (lane == t), wave-private lwx[g] ----
  {
    float acc[NH];
    #pragma unroll
    for (int h = 0; h < NH; h++) acc[h] = bsel[h];
    for (int k = 0; k < DI; k++) {
      float xk = lx[lane][k];
      #pragma unroll
      for (int h = 0; h < NH; h++) acc[h] = fmaf(Wsel[h*IND + k], xk, acc[h]);
    }
    #pragma unroll
    for (int h = 0; h < NH; h++) lwx[g][lane][h] = acc[h];
  }
  // (same-wave LDS visibility via lgkmcnt)

  // ---- register-resident recurrent weights + conv-data quadratic forms ----
  float wh[NH];
  #pragma unroll
  for (int j = 0; j < NH; j++) wh[j] = Wsel[hrow*IND + DI + j];

  // quadratic-form constants for (n0, n1, e1r, e1i) of wire hrow:
  //   v = U1.[c;s];  wire 0 uses (A0,A1)=(v0,v1); wires>=1 use ((v0+v1)/2,(v0-v1)/2)
  float3 Qn0, Qn1, Qer, Qei;
  {
    float U1[8];
    mkU(qp[hrow*3+0], qp[hrow*3+1], qp[hrow*3+2], U1);
    // rows of U1 as complex pairs
    float r00r=U1[0], r00i=U1[1], r01r=U1[2], r01i=U1[3];
    float r10r=U1[4], r10i=U1[5], r11r=U1[6], r11i=U1[7];
    float P0r,P0i,P1r,P1i, R0r,R0i,R1r,R1i;
    if (lane == 0) {
      P0r=r00r; P0i=r00i; P1r=r01r; P1i=r01i;
      R0r=r10r; R0i=r10i; R1r=r11r; R1i=r11i;
    } else {
      P0r=0.5f*(r00r+r10r); P0i=0.5f*(r00i+r10i);
      P1r=0.5f*(r01r+r11r); P1i=0.5f*(r01i+r11i);
      R0r=0.5f*(r00r-r10r); R0i=0.5f*(r00i-r10i);
      R1r=0.5f*(r01r-r11r); R1i=0.5f*(r01i-r11i);
    }
    Qn0 = qf(P0r*P0r+P0i*P0i, P1r*P1r+P1i*P1i, 2.f*(P0r*P1r+P0i*P1i));
    Qn1 = qf(R0r*R0r+R0i*R0i, R1r*R1r+R1i*R1i, 2.f*(R0r*R1r+R0i*R1i));
    Qer = qf(R0r*P0r+R0i*P0i, R1r*P1r+R1i*P1i,
             (R0r*P1r+R0i*P1i) + (R1r*P0r+R1i*P0i));
    Qei = qf(R0i*P0r-R0r*P0i, R1i*P1r-R1r*P1i,
             (R0i*P1r-R0r*P1i) + (R1i*P0r-R1r*P0i));
  }

  // ---- per-lane chain constants ----
  float4 b0 = *reinterpret_cast<const float4*>(&lBw[g][0][0]);
  if (hq == 0) b0 = make_float4(1.f, 1.f, 0.f, 0.f);   // E0 mask excludes wire 0
  float k0, k3, ka, kb;
  if      (sg == 0) { k0 = b0.x;  k3 = b0.y;  ka = b0.z; kb = -b0.w; }
  else if (sg == 1) { k0 = b0.z;  k3 = b0.z;  ka = 0.5f*(b0.x + b0.y); kb = 0.f; }
  else if (sg == 2) { k0 = -b0.w; k3 = b0.w;  ka = 0.f;  kb = 0.5f*(b0.y - b0.x); }
  else              { k0 = b0.y;  k3 = b0.x;  ka = b0.z; kb = b0.w; }
  const float pw = (sg == 1) ? 2.f : (sg == 2) ? -2.f : 1.f;

  float C00[9], C11[9], Cr[9], Ci[9];
  #pragma unroll
  for (int w = 1; w <= 9; w++) {
    float4 bb = *reinterpret_cast<const float4*>(&lBw[g][w][0]);
    bool inM = (hq == 0) || (w <= hq);        // M_0={1..9}, M_h={0..h}
    C00[w-1] = inM ? bb.x : 1.f;
    C11[w-1] = inM ? bb.y : 1.f;
    Cr[w-1]  = inM ? bb.z : 0.f;
    Ci[w-1]  = inM ? bb.w : 0.f;
  }

  float cstate = 0.f, hval = 0.f;
  float wxcur = lwx[g][0][hrow];      // prefetched W.x for t=0

  for (int t = 0; t < TS; t++) {
    const int tb = t & 1;

    // ---- (a) pre-activation: prefetched wx + tree-reduced recurrent dot ----
    float h0 = rl(hval,0), h1 = rl(hval,1), h2 = rl(hval,2), h3 = rl(hval,3), h4 = rl(hval,4);
    float h5 = rl(hval,5), h6 = rl(hval,6), h7 = rl(hval,7), h8 = rl(hval,8), h9 = rl(hval,9);
    float p0 = fmaf(wh[1], h1, wh[0]*h0);
    float p1 = fmaf(wh[3], h3, wh[2]*h2);
    float p2 = fmaf(wh[5], h5, wh[4]*h4);
    float p3 = fmaf(wh[7], h7, wh[6]*h6);
    float p4 = fmaf(wh[9], h9, wh[8]*h8);
    float pre = wxcur + ((p0 + p1) + (p2 + p3) + p4);

    // prefetch next step's W.x (latency hidden under the chain)
    wxcur = lwx[g][(t+1) & (TS-1)][hrow];

    // full-angle sin/cos, no range reduction (|pre| small); 1/2pi inline const
    float th = pre * 0.15915494309189535f;
    float S = __builtin_amdgcn_sinf(th);
    float C = __builtin_amdgcn_cosf(th);
    float n0v  = qeval(Qn0, C, S);
    float n1v  = qeval(Qn1, C, S);
    float e1rv = qeval(Qer, C, S);
    float e1iv = qeval(Qei, C, S);

    // ---- (c) chain with broadcasts interleaved at point of use ----
    float vx0 = rl(n0v,0), vy0 = rl(n1v,0), vr0 = rl(e1rv,0), vi0 = rl(e1iv,0);
    float r0 = k0*vx0;
    float r3 = k3*vy0;
    float a  = ka*vr0 - kb*vi0;
    float bz = ka*vi0 + kb*vr0;
    #pragma unroll
    for (int w = 1; w <= 9; w++) {
      float vxw = rl(n0v, w), vyw = rl(n1v, w), vrw = rl(e1rv, w), viw = rl(e1iv, w);
      float q  = r0 + r3,  t2a = a + a;
      float u0 = q + t2a,  u3 = q - t2a;
      float s  = r0 - r3,  bb = bz + bz;          // u1 = (s, -bb)
      float m0 = u0 * vxw;
      float m3 = u3 * vyw;
      float am = s*vrw + bb*viw;                  // Re(u1*e1)
      float bm = s*viw - bb*vrw;                  // Im(u1*e1)
      float q2 = m0 + m3,  t2m = am + am;
      float y0 = q2 + t2m, y3 = q2 - t2m;
      float s2 = m0 - m3,  b2 = bm + bm;          // y1 = (s2, -b2)
      r0 = y0 * C00[w-1];
      r3 = y3 * C11[w-1];
      a  = s2*Cr[w-1] - b2*Ci[w-1];               // Re(y1*conj(C01))
      bz = -(s2*Ci[w-1] + b2*Cr[w-1]);            // Im(y1*conj(C01))
    }

    // ---- (d) weighted pick + quad-sum; activation PRE-barrier ----
    float t0 = (sg & 1) ? a  : r0;
    float t1 = (sg & 1) ? r3 : bz;
    float Ee = ((sg & 2) ? t1 : t0) * pw;
    Ee += dppx<0xB1>(Ee);
    Ee += dppx<0x4E>(Ee);
    if ((lane & 3) == 0 && hq < NH) {
      lq[tb][hq][g] = (g == 2) ? tanhr(Ee) : sigm(Ee);
    }
    __syncthreads();   // the one barrier: activated-gate exchange

    // ---- (f) LSTM cell: single b128 broadcast read of (f,i,g,o) ----
    float4 gates = *reinterpret_cast<const float4*>(&lq[tb][hrow][0]);
    cstate = gates.x*cstate + gates.y*gates.z;
    hval = gates.w*tanhr(cstate);
    if (g == 0 && lane < NH) out[(size_t)t*(NB*NH) + b*NH + lane] = hval;
  }

  if (g == 0 && lane < NH) {
    out[(size_t)TS*NB*NH + b*NH + lane]          = hval;
    out[(size_t)TS*NB*NH + NB*NH + b*NH + lane]  = cstate;
  }
}

extern "C" void kernel_launch(void* const* d_in, const int* in_sizes, int n_in,
                              void* d_out, int out_size, void* d_ws, size_t ws_size,
                              hipStream_t stream) {
  (void)in_sizes; (void)n_in; (void)d_ws; (void)ws_size; (void)out_size;
  qlstm_kernel<<<dim3(NB), dim3(256), 0, stream>>>(
      (const float*)d_in[0], (const float*)d_in[1],
      (const float*)d_in[2], (const float*)d_in[3],
      (const float*)d_in[4], (const float*)d_in[5],
      (const float*)d_in[6], (const float*)d_in[7],
      (const float*)d_in[8], (const float*)d_in[9],
      (float*)d_out);
}